// Round 2
// baseline (536.189 us; speedup 1.0000x reference)
//
#include <hip/hip_runtime.h>

// DecisionGate:
//   g          = 1 / (1 + |x|^4)                      [4096, 64]  (A=1, 2B=4)
//   mask       = g >= 0.5                             [4096, 64]  (written as 0/1 float)
//   dispatched = (mask ? g : 0)[b,p] * act[b,d]       [4096, 64, 512]
//
// Output buffer layout (flat concat, float32):
//   [0 .. 262143]              g
//   [262144 .. 524287]         mask
//   [524288 .. 134742015]      dispatched
//
// Roofline: ~539 MB of writes dominates -> HBM-write-bound, ~86 us ideal.

constexpr int BATCH = 4096;
constexpr int P = 64;
constexpr int D = 512;

// Native vector type: __builtin_nontemporal_store accepts this (not HIP float4).
typedef float vfloat4 __attribute__((ext_vector_type(4)));

__global__ __launch_bounds__(128)
void decision_gate_kernel(const float* __restrict__ x,
                          const float* __restrict__ act,
                          float* __restrict__ g_out,
                          float* __restrict__ mask_out,
                          float* __restrict__ disp) {
    __shared__ float w[P];

    const int b = blockIdx.x;
    const int t = threadIdx.x;

    // --- gate computation: first 64 threads handle this row's 64 gates ---
    if (t < P) {
        const float xv = x[(size_t)b * P + t];
        const float x2 = xv * xv;
        const float x4 = x2 * x2;          // |x/A|^(2B) with A=1, B=2
        const float g  = 1.0f / (1.0f + x4);
        const bool  m  = (g >= 0.5f);
        g_out[(size_t)b * P + t]    = g;
        mask_out[(size_t)b * P + t] = m ? 1.0f : 0.0f;
        w[t] = m ? g : 0.0f;
    }
    __syncthreads();

    // --- dispatch: each thread owns one float4 (4 d-elements) of act[b] ---
    // 128 threads * 4 = 512 = D, so exactly one vfloat4 per thread.
    const vfloat4 a = reinterpret_cast<const vfloat4*>(act)[(size_t)b * (D / 4) + t];

    vfloat4* out = reinterpret_cast<vfloat4*>(disp) + (size_t)b * (P * D / 4) + t;

    #pragma unroll 8
    for (int p = 0; p < P; ++p) {
        const float wp = w[p];             // same-address LDS read -> broadcast, free
        vfloat4 v = a * wp;
        __builtin_nontemporal_store(v, out + (size_t)p * (D / 4));
    }
}

extern "C" void kernel_launch(void* const* d_in, const int* in_sizes, int n_in,
                              void* d_out, int out_size, void* d_ws, size_t ws_size,
                              hipStream_t stream) {
    const float* x   = (const float*)d_in[0];   // [4096, 64]
    const float* act = (const float*)d_in[1];   // [4096, 512]
    // d_in[2] = batch_inds (int64) -- not needed for the dense outputs.

    float* out      = (float*)d_out;
    float* g_out    = out;                       // 4096*64
    float* mask_out = out + (size_t)BATCH * P;   // 4096*64
    float* disp     = out + (size_t)2 * BATCH * P;

    decision_gate_kernel<<<BATCH, 128, 0, stream>>>(x, act, g_out, mask_out, disp);
}